// Round 8
// baseline (1360.608 us; speedup 1.0000x reference)
//
#include <hip/hip_runtime.h>
#include <float.h>
#include <math.h>

#define K_CODES 1024
#define ED 64
#define NTOK 131072
#define EPS_DOT 2e-4f   // EPS/2 in dot space (score = -2*dot); bound ~3.5e-5 -> 6x margin

typedef __attribute__((ext_vector_type(8)))  short short8;   // 8 bf16 (4 VGPRs)
typedef __attribute__((ext_vector_type(16))) float float16;  // MFMA 32x32 acc

// ---------------------------------------------------------------------------
// NUMERICS OF THE EXACT PATH ARE FROZEN (rounds 2-7 passed, 0 argmin flips):
//  - zsq / e_sq: numpy pairwise_sum n=64 (8 accs strided 8, mul+add no fma,
//    combine ((r0+r1)+(r2+r3))+((r4+r5)+(r6+r7))), contract(off).
//  - dot(z,e): single sequential fmaf chain over d=0..63.
//  - d2 = fmaf(-2,dot,zsq) + e_sq.
//  - argmin: smallest d2, smallest index on exact tie (np.argmin).
// Approx path (MFMA bf16 hi/lo, proven rounds 6-7) only classifies tokens:
// if 2nd-best approx dot is > EPS_DOT below best, the best is provably the
// exact argmin (error bound << EPS). Ambiguous tokens get a FULL exact scan
// in vq_rescue -> bit-identical indices in all cases.
// ---------------------------------------------------------------------------

static __device__ __forceinline__ unsigned short f2bf(float x) {  // RNE
    unsigned u = __float_as_uint(x);
    u += 0x7fffu + ((u >> 16) & 1u);
    return (unsigned short)(u >> 16);
}
static __device__ __forceinline__ float bf2f(unsigned short h) {
    return __uint_as_float(((unsigned)h) << 16);
}

// ---------------------------------------------------------------------------
// prep: 4 blocks x 256 -> codebook frags (layout proven rounds 6-7), frozen
// e_sq, zero counts; block0/tid0 zeroes sse + wcount.
// frag[(ct*8 + g)*32 + (k&31)], g = d/8.
// ---------------------------------------------------------------------------
__global__ __launch_bounds__(256) void vq_prep(const float* __restrict__ cb,
                                               float* __restrict__ e_sq,
                                               short8* __restrict__ efH,
                                               short8* __restrict__ efL,
                                               unsigned int* __restrict__ counts,
                                               float* __restrict__ sse,
                                               unsigned int* __restrict__ wcount)
{
#pragma clang fp contract(off)
    const int k = blockIdx.x * 256 + threadIdx.x;   // 0..1023
    const float4* ep = (const float4*)(cb + (size_t)k * ED);
    const int m = k & 31, ct = k >> 5;
    float r[8];
#pragma unroll
    for (int g = 0; g < 8; ++g) {
        float4 a = ep[2 * g], b = ep[2 * g + 1];
        float v[8] = {a.x, a.y, a.z, a.w, b.x, b.y, b.z, b.w};
        short8 hv, lv;
#pragma unroll
        for (int j = 0; j < 8; ++j) {
            unsigned short hb = f2bf(v[j]);
            hv[j] = (short)hb;
            lv[j] = (short)f2bf(v[j] - bf2f(hb));
            const float sq = v[j] * v[j];          // frozen pairwise e_sq
            r[j] = g ? (r[j] + sq) : sq;
        }
        efH[(ct * 8 + g) * 32 + m] = hv;
        efL[(ct * 8 + g) * 32 + m] = lv;
    }
    e_sq[k] = ((r[0] + r[1]) + (r[2] + r[3])) + ((r[4] + r[5]) + (r[6] + r[7]));
    counts[k] = 0u;
    if (k == 0) { *sse = 0.f; *wcount = 0u; }
}

// ---------------------------------------------------------------------------
// fused: block = 256 tokens. Stage z->LDS, convert bf16 hi/lo B-frags in
// regs, MFMA over all 32 code-tiles (ef from global, L2-resident, double-
// buffered), running (V1,I1,V2) per token. Unambiguous -> full epilogue
// here; ambiguous -> worklist.
// LDS: 256*68*4 + 4KB hist = 73.7 KB -> 2 blocks/CU.
// ---------------------------------------------------------------------------
__global__ __launch_bounds__(256, 2) void vq_fused(const float* __restrict__ z_e,
                                                   const float* __restrict__ cb,
                                                   const short8* __restrict__ efH,
                                                   const short8* __restrict__ efL,
                                                   float* __restrict__ out_zq,
                                                   float* __restrict__ out_idx,
                                                   unsigned int* __restrict__ counts,
                                                   float* __restrict__ sse,
                                                   unsigned int* __restrict__ wlist,
                                                   unsigned int* __restrict__ wcount)
{
#pragma clang fp contract(off)
    __shared__ __align__(16) float zs[256 * 68];   // [token][68] pad: 4-way max
    __shared__ unsigned int hist[K_CODES];
    __shared__ float wsum[4];

    const int tid = threadIdx.x;
    const int lane = tid & 63, wv = tid >> 6;
    const int ml = lane & 31, h = lane >> 5;
    const int t0 = blockIdx.x * 256;
    const int t  = t0 + tid;                       // this thread's token

    for (int i = tid; i < K_CODES; i += 256) hist[i] = 0u;

    // ---- stage z rows (thread <-> token) ----
    {
        const float4* zp = (const float4*)(z_e + (size_t)t * ED);
#pragma unroll
        for (int j = 0; j < 16; ++j)
            *(float4*)&zs[tid * 68 + 4 * j] = zp[j];
    }
    __syncthreads();

    // ---- convert B-frags (regs): wave wv owns tokens wv*64..+63 local,
    //      tile X in {0,1}; lane (ml,h) -> token wv*64+X*32+ml, d=(2q+h)*8+j
    short8 zh[2][4], zl[2][4];
#pragma unroll
    for (int X = 0; X < 2; ++X) {
        const int tok = wv * 64 + X * 32 + ml;
#pragma unroll
        for (int q = 0; q < 4; ++q) {
            const int g = q * 2 + h;
            const float* p = &zs[tok * 68 + g * 8];
            float4 a = *(const float4*)p, b = *(const float4*)(p + 4);
            float v[8] = {a.x, a.y, a.z, a.w, b.x, b.y, b.z, b.w};
            short8 hv, lv;
#pragma unroll
            for (int j = 0; j < 8; ++j) {
                unsigned short hb = f2bf(v[j]);
                hv[j] = (short)hb;
                lv[j] = (short)f2bf(v[j] - bf2f(hb));
            }
            zh[X][q] = hv;
            zl[X][q] = lv;
        }
    }

    // ---- MFMA over 32 code-tiles with running 2-min trackers ----
    float V1[2] = {-FLT_MAX, -FLT_MAX}, V2[2] = {-FLT_MAX, -FLT_MAX};
    int   I1[2] = {0, 0};

    short8 ecur[8], enxt[8];                       // [0..3]=H, [4..7]=L
#pragma unroll
    for (int q = 0; q < 4; ++q) {
        const int idx = (0 * 8 + q * 2 + h) * 32 + ml;
        ecur[q] = efH[idx]; ecur[4 + q] = efL[idx];
    }

    for (int ct = 0; ct < 32; ++ct) {
        if (ct < 31) {
#pragma unroll
            for (int q = 0; q < 4; ++q) {
                const int idx = ((ct + 1) * 8 + q * 2 + h) * 32 + ml;
                enxt[q] = efH[idx]; enxt[4 + q] = efL[idx];
            }
        }
        float16 acc0 = {}, acc1 = {};
#pragma unroll
        for (int q = 0; q < 4; ++q) {              // order proven r6-7: hh,hl,lh
            acc0 = __builtin_amdgcn_mfma_f32_32x32x16_bf16(ecur[q],     zh[0][q], acc0, 0, 0, 0);
            acc1 = __builtin_amdgcn_mfma_f32_32x32x16_bf16(ecur[q],     zh[1][q], acc1, 0, 0, 0);
            acc0 = __builtin_amdgcn_mfma_f32_32x32x16_bf16(ecur[q],     zl[0][q], acc0, 0, 0, 0);
            acc1 = __builtin_amdgcn_mfma_f32_32x32x16_bf16(ecur[q],     zl[1][q], acc1, 0, 0, 0);
            acc0 = __builtin_amdgcn_mfma_f32_32x32x16_bf16(ecur[4 + q], zh[0][q], acc0, 0, 0, 0);
            acc1 = __builtin_amdgcn_mfma_f32_32x32x16_bf16(ecur[4 + q], zh[1][q], acc1, 0, 0, 0);
        }
#pragma unroll
        for (int X = 0; X < 2; ++X) {
            const float16 acc = X ? acc1 : acc0;
            float v1 = -FLT_MAX, v2 = -FLT_MAX;
            int i1 = 0;
#pragma unroll
            for (int rg = 0; rg < 16; ++rg) {
                const float v = acc[rg];
                const int mrow = (rg & 3) + 8 * (rg >> 2) + 4 * h;  // C/D row
                if (v > v1) { v2 = v1; v1 = v; i1 = mrow; }
                else v2 = fmaxf(v2, v);
            }
            const float o1 = __shfl_xor(v1, 32);
            const float o2 = __shfl_xor(v2, 32);
            const int   oi = __shfl_xor(i1, 32);
            const float lo = fminf(v1, o1);
            if (o1 > v1) { v1 = o1; i1 = oi; }
            v2 = fmaxf(lo, fmaxf(v2, o2));         // exact tile 2nd-largest
            // running update (ct ascending; ties stay ambiguous via V2)
            if (v1 > V1[X]) { V2[X] = fmaxf(V1[X], v2); V1[X] = v1; I1[X] = ct * 32 + i1; }
            else            { V2[X] = fmaxf(V2[X], v1); }
        }
#pragma unroll
        for (int i = 0; i < 8; ++i) ecur[i] = enxt[i];
    }

    // this thread's token = local token tid = wv*64 + h*32 + ml -> tile X = h
    const float v1f = V1[h], v2f = V2[h];
    const int   i1f = I1[h];
    const bool amb = (v2f >= v1f - EPS_DOT);

    float lsse = 0.f;
    if (!amb) {
        const int bi = i1f;                        // provably exact argmin
        atomicAdd(&hist[bi], 1u);
        out_idx[t] = (float)bi;
        const float4* eq = (const float4*)(cb + (size_t)bi * ED);
        float4* oz = (float4*)(out_zq + (size_t)t * ED);
#pragma unroll
        for (int i = 0; i < 16; ++i) {
            float4 q = eq[i];
            oz[i] = q;
            const float* zrow = &zs[tid * 68 + 4 * i];
            float dx = q.x - zrow[0]; lsse = fmaf(dx, dx, lsse);
            float dy = q.y - zrow[1]; lsse = fmaf(dy, dy, lsse);
            float dz = q.z - zrow[2]; lsse = fmaf(dz, dz, lsse);
            float dw = q.w - zrow[3]; lsse = fmaf(dw, dw, lsse);
        }
    } else {
        const unsigned pos = atomicAdd(wcount, 1u);
        wlist[pos] = (unsigned)t;
    }

    // block SSE reduce (unambiguous tokens only)
#pragma unroll
    for (int off = 32; off > 0; off >>= 1)
        lsse += __shfl_down(lsse, off, 64);
    if (lane == 0) wsum[wv] = lsse;
    __syncthreads();
    if (tid == 0)
        atomicAdd(sse, (wsum[0] + wsum[1]) + (wsum[2] + wsum[3]));
    for (int i = tid; i < K_CODES; i += 256) {
        const unsigned int c = hist[i];
        if (c) atomicAdd(&counts[i], c);
    }
}

// ---------------------------------------------------------------------------
// rescue: one wave per ambiguous token; FULL exact scan of all 1024 codes
// with the frozen chain (bit-identical to reference) + coalesced epilogue.
// ---------------------------------------------------------------------------
__global__ __launch_bounds__(256) void vq_rescue(const float* __restrict__ z_e,
                                                 const float* __restrict__ cb,
                                                 const float* __restrict__ e_sq,
                                                 const unsigned int* __restrict__ wlist,
                                                 const unsigned int* __restrict__ wcount,
                                                 float* __restrict__ out_zq,
                                                 float* __restrict__ out_idx,
                                                 unsigned int* __restrict__ counts,
                                                 float* __restrict__ sse)
{
#pragma clang fp contract(off)
    const int tid = threadIdx.x, lane = tid & 63, wv = tid >> 6;
    const int wave = blockIdx.x * 4 + wv, nw = gridDim.x * 4;
    const int n = (int)*wcount;

    for (int it = wave; it < n; it += nw) {
        const int t = (int)wlist[it];
        // z row: uniform addresses -> broadcast loads; replicate per lane
        const float4* zp = (const float4*)(z_e + (size_t)t * ED);
        float zr[ED];
#pragma unroll
        for (int j = 0; j < 16; ++j) {
            float4 v = zp[j];
            zr[4 * j + 0] = v.x; zr[4 * j + 1] = v.y;
            zr[4 * j + 2] = v.z; zr[4 * j + 3] = v.w;
        }
        // frozen pairwise zsq (identical on all lanes)
        float r[8];
#pragma unroll
        for (int j = 0; j < 8; ++j) r[j] = zr[j] * zr[j];
#pragma unroll
        for (int i = 8; i < ED; i += 8)
#pragma unroll
            for (int j = 0; j < 8; ++j) r[j] = r[j] + zr[i + j] * zr[i + j];
        const float zsq =
            ((r[0] + r[1]) + (r[2] + r[3])) + ((r[4] + r[5]) + (r[6] + r[7]));

        float best = FLT_MAX;
        int bi = K_CODES;
        for (int cc = 0; cc < 16; ++cc) {
            const int c = cc * 64 + lane;
            const float4* e4 = (const float4*)(cb + (size_t)c * ED);
            float eb[ED];
#pragma unroll
            for (int j = 0; j < 16; ++j) {
                float4 v = e4[j];
                eb[4 * j + 0] = v.x; eb[4 * j + 1] = v.y;
                eb[4 * j + 2] = v.z; eb[4 * j + 3] = v.w;
            }
            float a = 0.f;
#pragma unroll
            for (int d = 0; d < ED; ++d) a = fmaf(zr[d], eb[d], a);   // frozen
            const float d2 = fmaf(-2.f, a, zsq) + e_sq[c];
            if (d2 < best || (d2 == best && c < bi)) { best = d2; bi = c; }
        }
        // wave lexicographic (value, index) min-reduce = np.argmin
#pragma unroll
        for (int off = 32; off > 0; off >>= 1) {
            const float ov = __shfl_xor(best, off);
            const int   oi = __shfl_xor(bi, off);
            if (ov < best || (ov == best && oi < bi)) { best = ov; bi = oi; }
        }
        // epilogue: lane <-> d, coalesced
        const float qd = cb[(size_t)bi * ED + lane];
        const float zd = z_e[(size_t)t * ED + lane];
        out_zq[(size_t)t * ED + lane] = qd;
        float s = (qd - zd) * (qd - zd);
#pragma unroll
        for (int off = 32; off > 0; off >>= 1)
            s += __shfl_down(s, off, 64);
        if (lane == 0) {
            atomicAdd(sse, s);
            atomicAdd(&counts[bi], 1u);
            out_idx[t] = (float)bi;
        }
    }
}

// ---------------------------------------------------------------------------
// final: entropy / losses scalars
// ---------------------------------------------------------------------------
__global__ __launch_bounds__(1024) void vq_final(const unsigned int* __restrict__ counts,
                                                 const float* __restrict__ sse,
                                                 float* __restrict__ out_sc)
{
    __shared__ float red[1024];
    const int i = threadIdx.x;
    const float c = (float)counts[i];
    const float p = c / (float)NTOK + 1e-10f;
    red[i] = p * logf(p);
    __syncthreads();
    for (int s = 512; s > 0; s >>= 1) {
        if (i < s) red[i] += red[i + s];
        __syncthreads();
    }
    if (i == 0) {
        const float entropy = -red[0];
        const float cbl = (*sse) / ((float)NTOK * (float)ED);
        out_sc[0] = cbl;                                   // codebook_loss
        out_sc[1] = 0.25f * cbl;                           // commitment_loss
        out_sc[2] = -0.1f * (entropy / 6.93147180559945f); // entropy_loss
        out_sc[3] = expf(entropy);                         // perplexity
    }
}

// ---------------------------------------------------------------------------
extern "C" void kernel_launch(void* const* d_in, const int* in_sizes, int n_in,
                              void* d_out, int out_size, void* d_ws, size_t ws_size,
                              hipStream_t stream)
{
    const float* z_e = (const float*)d_in[0];
    const float* cb  = (const float*)d_in[1];

    float* out   = (float*)d_out;
    float* o_zq  = out;                              // [131072,64]
    float* o_idx = out + (size_t)NTOK * ED;          // [131072] (as float)
    float* o_sc  = o_idx + NTOK;                     // 4 scalars

    char* ws = (char*)d_ws;
    float*        e_sq   = (float*)(ws);                     // 4 KB
    unsigned int* counts = (unsigned int*)(ws + 4096);       // 4 KB
    float*        sse    = (float*)(ws + 8192);              // 4 B
    unsigned int* wcount = (unsigned int*)(ws + 8196);       // 4 B
    unsigned int* wlist  = (unsigned int*)(ws + 12288);      // 512 KB
    short8*       efH    = (short8*)(ws + 540672);           // 128 KB
    short8*       efL    = (short8*)(ws + 671744);           // 128 KB

    vq_prep  <<<4, 256, 0, stream>>>(cb, e_sq, efH, efL, counts, sse, wcount);
    vq_fused <<<NTOK / 256, 256, 0, stream>>>(z_e, cb, efH, efL,
                                              o_zq, o_idx, counts, sse,
                                              wlist, wcount);
    vq_rescue<<<128, 256, 0, stream>>>(z_e, cb, e_sq, wlist, wcount,
                                       o_zq, o_idx, counts, sse);
    vq_final <<<1, 1024, 0, stream>>>(counts, sse, o_sc);
}

// Round 9
// 782.533 us; speedup vs baseline: 1.7387x; 1.7387x over previous
//
#include <hip/hip_runtime.h>
#include <float.h>
#include <math.h>

#define K_CODES 1024
#define ED 64
#define NTOK 131072
#define EPS_DOT 5e-5f   // score-space band; worst-case approx err ~5e-6 -> 10x margin

typedef __attribute__((ext_vector_type(8)))  short short8;   // 8 bf16 (4 VGPRs)
typedef __attribute__((ext_vector_type(16))) float float16;  // MFMA 32x32 acc

// ---------------------------------------------------------------------------
// NUMERICS OF THE EXACT PATH ARE FROZEN (rounds 2-8 passed, 0 argmin flips):
//  - zsq / e_sq: numpy pairwise_sum n=64 (8 accs strided 8, mul+add no fma,
//    combine ((r0+r1)+(r2+r3))+((r4+r5)+(r6+r7))), contract(off).
//  - dot(z,e): single sequential fmaf chain over d=0..63.
//  - d2 = fmaf(-2,dot,zsq) + e_sq.
//  - argmin: smallest d2, smallest index on exact tie (np.argmin).
// Approx path (MFMA bf16 hi/lo) classifies tokens. Score now includes the
// -e_sq/2 term via an extra rank-2 MFMA (bias removed -> tight EPS). If the
// 2nd-best score is > EPS_DOT below best, best is provably the exact argmin.
// Ambiguous tokens get a FULL exact 1024-code scan in vq_rescue.
// Round-8 lesson: rescue MUST NOT hold e-row arrays in registers (VGPR=84
// spilled zr+eb to scratch -> 1226us). Stream the row; launch_bounds(256,1).
// ---------------------------------------------------------------------------

static __device__ __forceinline__ unsigned short f2bf(float x) {  // RNE
    unsigned u = __float_as_uint(x);
    u += 0x7fffu + ((u >> 16) & 1u);
    return (unsigned short)(u >> 16);
}
static __device__ __forceinline__ float bf2f(unsigned short h) {
    return __uint_as_float(((unsigned)h) << 16);
}

// ---------------------------------------------------------------------------
// prep: codebook frags + packed bf16 hi/lo of -e_sq/2 + frozen e_sq.
// frag[(ct*8 + g)*32 + (k&31)], g = d/8.
// ---------------------------------------------------------------------------
__global__ __launch_bounds__(256) void vq_prep(const float* __restrict__ cb,
                                               float* __restrict__ e_sq,
                                               short8* __restrict__ efH,
                                               short8* __restrict__ efL,
                                               unsigned int* __restrict__ efQ,
                                               unsigned int* __restrict__ counts,
                                               float* __restrict__ sse,
                                               unsigned int* __restrict__ wcount)
{
#pragma clang fp contract(off)
    const int k = blockIdx.x * 256 + threadIdx.x;   // 0..1023
    const float4* ep = (const float4*)(cb + (size_t)k * ED);
    const int m = k & 31, ct = k >> 5;
    float r[8];
#pragma unroll
    for (int g = 0; g < 8; ++g) {
        float4 a = ep[2 * g], b = ep[2 * g + 1];
        float v[8] = {a.x, a.y, a.z, a.w, b.x, b.y, b.z, b.w};
        short8 hv, lv;
#pragma unroll
        for (int j = 0; j < 8; ++j) {
            unsigned short hb = f2bf(v[j]);
            hv[j] = (short)hb;
            lv[j] = (short)f2bf(v[j] - bf2f(hb));
            const float sq = v[j] * v[j];          // frozen pairwise e_sq
            r[j] = g ? (r[j] + sq) : sq;
        }
        efH[(ct * 8 + g) * 32 + m] = hv;
        efL[(ct * 8 + g) * 32 + m] = lv;
    }
    const float es = ((r[0] + r[1]) + (r[2] + r[3])) + ((r[4] + r[5]) + (r[6] + r[7]));
    e_sq[k] = es;
    const float s = -0.5f * es;                    // exact scale
    const unsigned short sh = f2bf(s);
    const unsigned short sl = f2bf(s - bf2f(sh));
    efQ[k] = (unsigned)sh | ((unsigned)sl << 16);
    counts[k] = 0u;
    if (k == 0) { *sse = 0.f; *wcount = 0u; }
}

// ---------------------------------------------------------------------------
// fused: block = 256 tokens. Stage z->LDS, bf16 hi/lo B-frags in regs, MFMA
// over 32 code-tiles (3 dot products + 1 esq-bias MFMA per tile), running
// (V1,I1,V2) per token on score = dot - e_sq/2. Unambiguous -> epilogue
// here; ambiguous -> worklist.  LDS ~73.7 KB -> 2 blocks/CU.
// ---------------------------------------------------------------------------
__global__ __launch_bounds__(256, 2) void vq_fused(const float* __restrict__ z_e,
                                                   const float* __restrict__ cb,
                                                   const short8* __restrict__ efH,
                                                   const short8* __restrict__ efL,
                                                   const unsigned int* __restrict__ efQ,
                                                   float* __restrict__ out_zq,
                                                   float* __restrict__ out_idx,
                                                   unsigned int* __restrict__ counts,
                                                   float* __restrict__ sse,
                                                   unsigned int* __restrict__ wlist,
                                                   unsigned int* __restrict__ wcount)
{
#pragma clang fp contract(off)
    __shared__ __align__(16) float zs[256 * 68];   // [token][68]
    __shared__ unsigned int hist[K_CODES];
    __shared__ float wsum[4];

    const int tid = threadIdx.x;
    const int lane = tid & 63, wv = tid >> 6;
    const int ml = lane & 31, h = lane >> 5;
    const int t0 = blockIdx.x * 256;
    const int t  = t0 + tid;                       // this thread's token

    for (int i = tid; i < K_CODES; i += 256) hist[i] = 0u;

    // ---- stage z rows (thread <-> token) ----
    {
        const float4* zp = (const float4*)(z_e + (size_t)t * ED);
#pragma unroll
        for (int j = 0; j < 16; ++j)
            *(float4*)&zs[tid * 68 + 4 * j] = zp[j];
    }
    __syncthreads();

    // ---- convert B-frags (regs): lane (ml,h) -> token wv*64+X*32+ml ----
    short8 zh[2][4], zl[2][4];
#pragma unroll
    for (int X = 0; X < 2; ++X) {
        const int tok = wv * 64 + X * 32 + ml;
#pragma unroll
        for (int q = 0; q < 4; ++q) {
            const int g = q * 2 + h;
            const float* p = &zs[tok * 68 + g * 8];
            float4 a = *(const float4*)p, b = *(const float4*)(p + 4);
            float v[8] = {a.x, a.y, a.z, a.w, b.x, b.y, b.z, b.w};
            short8 hv, lv;
#pragma unroll
            for (int j = 0; j < 8; ++j) {
                unsigned short hb = f2bf(v[j]);
                hv[j] = (short)hb;
                lv[j] = (short)f2bf(v[j] - bf2f(hb));
            }
            zh[X][q] = hv;
            zl[X][q] = lv;
        }
    }

    // ones B-frag for the esq-bias MFMA (k=0,1 slots, h=0 half only)
    short8 onesf = {0, 0, 0, 0, 0, 0, 0, 0};
    if (h == 0) { onesf[0] = (short)0x3F80; onesf[1] = (short)0x3F80; }

    // ---- MFMA over 32 code-tiles with running 2-max trackers ----
    float V1[2] = {-FLT_MAX, -FLT_MAX}, V2[2] = {-FLT_MAX, -FLT_MAX};
    int   I1[2] = {0, 0};

    short8 ecur[8], enxt[8];                       // [0..3]=H, [4..7]=L
    unsigned qcur, qnxt;
#pragma unroll
    for (int q = 0; q < 4; ++q) {
        const int idx = (q * 2 + h) * 32 + ml;
        ecur[q] = efH[idx]; ecur[4 + q] = efL[idx];
    }
    qcur = efQ[ml];

    for (int ct = 0; ct < 32; ++ct) {
        if (ct < 31) {
#pragma unroll
            for (int q = 0; q < 4; ++q) {
                const int idx = ((ct + 1) * 8 + q * 2 + h) * 32 + ml;
                enxt[q] = efH[idx]; enxt[4 + q] = efL[idx];
            }
            qnxt = efQ[(ct + 1) * 32 + ml];
        }
        // esq-bias A-frag (h=0 half: k=0 -> hi, k=1 -> lo)
        short8 esqf = {0, 0, 0, 0, 0, 0, 0, 0};
        if (h == 0) { esqf[0] = (short)(qcur & 0xFFFFu); esqf[1] = (short)(qcur >> 16); }

        float16 acc0 = {}, acc1 = {};
        acc0 = __builtin_amdgcn_mfma_f32_32x32x16_bf16(esqf, onesf, acc0, 0, 0, 0);
        acc1 = __builtin_amdgcn_mfma_f32_32x32x16_bf16(esqf, onesf, acc1, 0, 0, 0);
#pragma unroll
        for (int q = 0; q < 4; ++q) {              // proven order: hh, hl, lh
            acc0 = __builtin_amdgcn_mfma_f32_32x32x16_bf16(ecur[q],     zh[0][q], acc0, 0, 0, 0);
            acc1 = __builtin_amdgcn_mfma_f32_32x32x16_bf16(ecur[q],     zh[1][q], acc1, 0, 0, 0);
            acc0 = __builtin_amdgcn_mfma_f32_32x32x16_bf16(ecur[q],     zl[0][q], acc0, 0, 0, 0);
            acc1 = __builtin_amdgcn_mfma_f32_32x32x16_bf16(ecur[q],     zl[1][q], acc1, 0, 0, 0);
            acc0 = __builtin_amdgcn_mfma_f32_32x32x16_bf16(ecur[4 + q], zh[0][q], acc0, 0, 0, 0);
            acc1 = __builtin_amdgcn_mfma_f32_32x32x16_bf16(ecur[4 + q], zh[1][q], acc1, 0, 0, 0);
        }
#pragma unroll
        for (int X = 0; X < 2; ++X) {
            const float16 acc = X ? acc1 : acc0;
            float v1 = -FLT_MAX, v2 = -FLT_MAX;
            int i1 = 0;
#pragma unroll
            for (int rg = 0; rg < 16; ++rg) {
                const float v = acc[rg];
                const int mrow = (rg & 3) + 8 * (rg >> 2) + 4 * h;  // C/D row
                if (v > v1) { v2 = v1; v1 = v; i1 = mrow; }
                else v2 = fmaxf(v2, v);
            }
            const float o1 = __shfl_xor(v1, 32);
            const float o2 = __shfl_xor(v2, 32);
            const int   oi = __shfl_xor(i1, 32);
            const float lo = fminf(v1, o1);
            if (o1 > v1) { v1 = o1; i1 = oi; }
            v2 = fmaxf(lo, fmaxf(v2, o2));         // exact tile 2nd-largest
            if (v1 > V1[X]) { V2[X] = fmaxf(V1[X], v2); V1[X] = v1; I1[X] = ct * 32 + i1; }
            else            { V2[X] = fmaxf(V2[X], v1); }
        }
#pragma unroll
        for (int i = 0; i < 8; ++i) ecur[i] = enxt[i];
        qcur = qnxt;
    }

    // thread tid's token: local = wv*64 + h*32 + ml -> tile X = h, col = ml
    const float v1f = V1[h], v2f = V2[h];
    const int   i1f = I1[h];
    const bool amb = (v2f >= v1f - EPS_DOT);

    float lsse = 0.f;
    if (!amb) {
        const int bi = i1f;                        // provably exact argmin
        atomicAdd(&hist[bi], 1u);
        out_idx[t] = (float)bi;
        const float4* eq = (const float4*)(cb + (size_t)bi * ED);
        float4* oz = (float4*)(out_zq + (size_t)t * ED);
#pragma unroll
        for (int i = 0; i < 16; ++i) {
            float4 q = eq[i];
            oz[i] = q;
            const float* zrow = &zs[tid * 68 + 4 * i];
            float dx = q.x - zrow[0]; lsse = fmaf(dx, dx, lsse);
            float dy = q.y - zrow[1]; lsse = fmaf(dy, dy, lsse);
            float dz = q.z - zrow[2]; lsse = fmaf(dz, dz, lsse);
            float dw = q.w - zrow[3]; lsse = fmaf(dw, dw, lsse);
        }
    } else {
        const unsigned pos = atomicAdd(wcount, 1u);
        wlist[pos] = (unsigned)t;
    }

    // block SSE reduce (unambiguous tokens only)
#pragma unroll
    for (int off = 32; off > 0; off >>= 1)
        lsse += __shfl_down(lsse, off, 64);
    if (lane == 0) wsum[wv] = lsse;
    __syncthreads();
    if (tid == 0)
        atomicAdd(sse, (wsum[0] + wsum[1]) + (wsum[2] + wsum[3]));
    for (int i = tid; i < K_CODES; i += 256) {
        const unsigned int c = hist[i];
        if (c) atomicAdd(&counts[i], c);
    }
}

// ---------------------------------------------------------------------------
// rescue: one wave per ambiguous token; FULL exact 1024-code scan with the
// frozen chain. E-row STREAMED float4-wise (no register array -> no spill).
// ---------------------------------------------------------------------------
__global__ __launch_bounds__(256, 1) void vq_rescue(const float* __restrict__ z_e,
                                                    const float* __restrict__ cb,
                                                    const float* __restrict__ e_sq,
                                                    const unsigned int* __restrict__ wlist,
                                                    const unsigned int* __restrict__ wcount,
                                                    float* __restrict__ out_zq,
                                                    float* __restrict__ out_idx,
                                                    unsigned int* __restrict__ counts,
                                                    float* __restrict__ sse)
{
#pragma clang fp contract(off)
    const int tid = threadIdx.x, lane = tid & 63, wv = tid >> 6;
    const int wave = blockIdx.x * 4 + wv, nw = gridDim.x * 4;
    const int n = (int)*wcount;

    for (int it = wave; it < n; it += nw) {
        const int t = (int)wlist[it];
        // z row (wave-uniform addresses)
        const float4* zp = (const float4*)(z_e + (size_t)t * ED);
        float zr[ED];
#pragma unroll
        for (int j = 0; j < 16; ++j) {
            float4 v = zp[j];
            zr[4 * j + 0] = v.x; zr[4 * j + 1] = v.y;
            zr[4 * j + 2] = v.z; zr[4 * j + 3] = v.w;
        }
        // frozen pairwise zsq
        float r[8];
#pragma unroll
        for (int j = 0; j < 8; ++j) r[j] = zr[j] * zr[j];
#pragma unroll
        for (int i = 8; i < ED; i += 8)
#pragma unroll
            for (int j = 0; j < 8; ++j) r[j] = r[j] + zr[i + j] * zr[i + j];
        const float zsq =
            ((r[0] + r[1]) + (r[2] + r[3])) + ((r[4] + r[5]) + (r[6] + r[7]));

        float best = FLT_MAX;
        int bi = K_CODES;
        for (int cc = 0; cc < 16; ++cc) {
            const int c = cc * 64 + lane;
            const float4* e4 = (const float4*)(cb + (size_t)c * ED);
            float a = 0.f;
#pragma unroll 4
            for (int j = 0; j < 16; ++j) {         // streamed: no eb[] array
                const float4 v = e4[j];
                a = fmaf(zr[4 * j + 0], v.x, a);   // frozen sequential chain
                a = fmaf(zr[4 * j + 1], v.y, a);
                a = fmaf(zr[4 * j + 2], v.z, a);
                a = fmaf(zr[4 * j + 3], v.w, a);
            }
            const float d2 = fmaf(-2.f, a, zsq) + e_sq[c];
            if (d2 < best || (d2 == best && c < bi)) { best = d2; bi = c; }
        }
        // wave lexicographic (value, index) min-reduce = np.argmin
#pragma unroll
        for (int off = 32; off > 0; off >>= 1) {
            const float ov = __shfl_xor(best, off);
            const int   oi = __shfl_xor(bi, off);
            if (ov < best || (ov == best && oi < bi)) { best = ov; bi = oi; }
        }
        // epilogue: lane <-> d, coalesced
        const float qd = cb[(size_t)bi * ED + lane];
        const float zd = z_e[(size_t)t * ED + lane];
        out_zq[(size_t)t * ED + lane] = qd;
        float s = (qd - zd) * (qd - zd);
#pragma unroll
        for (int off = 32; off > 0; off >>= 1)
            s += __shfl_down(s, off, 64);
        if (lane == 0) {
            atomicAdd(sse, s);
            atomicAdd(&counts[bi], 1u);
            out_idx[t] = (float)bi;
        }
    }
}

// ---------------------------------------------------------------------------
// final: entropy / losses scalars
// ---------------------------------------------------------------------------
__global__ __launch_bounds__(1024) void vq_final(const unsigned int* __restrict__ counts,
                                                 const float* __restrict__ sse,
                                                 float* __restrict__ out_sc)
{
    __shared__ float red[1024];
    const int i = threadIdx.x;
    const float c = (float)counts[i];
    const float p = c / (float)NTOK + 1e-10f;
    red[i] = p * logf(p);
    __syncthreads();
    for (int s = 512; s > 0; s >>= 1) {
        if (i < s) red[i] += red[i + s];
        __syncthreads();
    }
    if (i == 0) {
        const float entropy = -red[0];
        const float cbl = (*sse) / ((float)NTOK * (float)ED);
        out_sc[0] = cbl;                                   // codebook_loss
        out_sc[1] = 0.25f * cbl;                           // commitment_loss
        out_sc[2] = -0.1f * (entropy / 6.93147180559945f); // entropy_loss
        out_sc[3] = expf(entropy);                         // perplexity
    }
}

// ---------------------------------------------------------------------------
extern "C" void kernel_launch(void* const* d_in, const int* in_sizes, int n_in,
                              void* d_out, int out_size, void* d_ws, size_t ws_size,
                              hipStream_t stream)
{
    const float* z_e = (const float*)d_in[0];
    const float* cb  = (const float*)d_in[1];

    float* out   = (float*)d_out;
    float* o_zq  = out;                              // [131072,64]
    float* o_idx = out + (size_t)NTOK * ED;          // [131072] (as float)
    float* o_sc  = o_idx + NTOK;                     // 4 scalars

    char* ws = (char*)d_ws;
    float*        e_sq   = (float*)(ws);                     // 4 KB
    unsigned int* counts = (unsigned int*)(ws + 4096);       // 4 KB
    float*        sse    = (float*)(ws + 8192);              // 4 B
    unsigned int* wcount = (unsigned int*)(ws + 8196);       // 4 B
    unsigned int* efQ    = (unsigned int*)(ws + 12288);      // 4 KB
    unsigned int* wlist  = (unsigned int*)(ws + 16384);      // 512 KB
    short8*       efH    = (short8*)(ws + 544768);           // 128 KB
    short8*       efL    = (short8*)(ws + 675840);           // 128 KB

    vq_prep  <<<4, 256, 0, stream>>>(cb, e_sq, efH, efL, efQ, counts, sse, wcount);
    vq_fused <<<NTOK / 256, 256, 0, stream>>>(z_e, cb, efH, efL, efQ,
                                              o_zq, o_idx, counts, sse,
                                              wlist, wcount);
    vq_rescue<<<128, 256, 0, stream>>>(z_e, cb, e_sq, wlist, wcount,
                                       o_zq, o_idx, counts, sse);
    vq_final <<<1, 1024, 0, stream>>>(counts, sse, o_sc);
}